// Round 1
// 13941.591 us; speedup vs baseline: 1.7182x; 1.7182x over previous
//
#include <hip/hip_runtime.h>
#include <stdint.h>
#include <stddef.h>

// ---------------- problem constants ----------------
#define Bb 64
#define Tt 1024
#define Hh 512
#define Ll 4
#define Gg 2048                 // 4*H
#define NSTEPS (Tt + Ll - 1)    // 1027 wavefront steps
#define NBLK 256                // 64 blocks per layer-group x 4 layers
#define NTHR 256                // 4 waves
#define JBLK 8                  // hidden units per block
#define JROW 520                // padded LDS weight row (bf16): 512 + 8
#define GRP 64                  // blocks per layer group
#define CTR_BYTES (((Ll * NSTEPS * 4) + 127) & ~127)   // per-layer step counters
#define HBUF_ELEMS ((size_t)Ll * 2 * Bb * Hh)          // bf16 elements

typedef __bf16 bfrag __attribute__((ext_vector_type(8)));   // 8 bf16 = 4 VGPR (MFMA A/B)
typedef float f32x4 __attribute__((ext_vector_type(4)));    // MFMA C/D
typedef uint64_t u64;

__device__ __forceinline__ float sigm(float x) { return 1.0f / (1.0f + __expf(-x)); }
__device__ __forceinline__ float tanh_(float x) {
    float ax = fabsf(x);
    float e = __expf(-2.0f * ax);
    float r = (1.0f - e) / (1.0f + e);
    return copysignf(r, x);
}

__device__ __forceinline__ void pack8(const float4& x0, const float4& x1, __bf16* dst) {
    union { __bf16 h[8]; uint4 u; } o;
    o.h[0] = (__bf16)x0.x; o.h[1] = (__bf16)x0.y;
    o.h[2] = (__bf16)x0.z; o.h[3] = (__bf16)x0.w;
    o.h[4] = (__bf16)x1.x; o.h[5] = (__bf16)x1.y;
    o.h[6] = (__bf16)x1.z; o.h[7] = (__bf16)x1.w;
    *reinterpret_cast<uint4*>(dst) = o.u;
}

// 16B h-fragment load that bypasses L1+L2 (reads the IF$/memory coherent point).
// Relaxed atomic u64 pair: compiler tracks vmcnt, keeps loads pipelined.
__device__ __forceinline__ bfrag load_h16(const __bf16* p) {
    union { u64 q[2]; bfrag f; } u;
    const u64* qp = reinterpret_cast<const u64*>(p);
    u.q[0] = __hip_atomic_load(qp,     __ATOMIC_RELAXED, __HIP_MEMORY_SCOPE_SYSTEM);
    u.q[1] = __hip_atomic_load(qp + 1, __ATOMIC_RELAXED, __HIP_MEMORY_SCOPE_SYSTEM);
    return u.f;
}

__device__ __forceinline__ void wait_ge(const uint32_t* p, uint32_t v) {
    while (__hip_atomic_load(p, __ATOMIC_RELAXED, __HIP_MEMORY_SCOPE_AGENT) < v) {
        __builtin_amdgcn_s_sleep(1);
    }
}

__global__ __launch_bounds__(NTHR, 1)
void lstm_persistent(const float* __restrict__ inp,    // [B,T,H] fp32
                     const float* __restrict__ Wih,    // [L,4H,H] fp32
                     const float* __restrict__ Whh,    // [L,4H,H] fp32
                     const float* __restrict__ bih,    // [L,4H] fp32
                     const float* __restrict__ bhh,    // [L,4H] fp32
                     float* __restrict__ out,          // fp32: [T,B,H] + L*(h,c)[B,H]
                     uint32_t* __restrict__ ctr,       // [L][NSTEPS] per-layer counters (zeroed)
                     __bf16* __restrict__ hbuf)        // [L][2][B][H] bf16 (zeroed)
{
    const int tid  = threadIdx.x;
    const int bx   = blockIdx.x;
    const int l    = bx >> 6;        // layer group 0..3
    const int q    = bx & 63;        // slice within group
    const int j0   = q * JBLK;       // hidden base for this block
    const int w    = tid >> 6;       // wave id == M-tile (batch rows 16w..16w+15)
    const int lane = tid & 63;
    const int ln16 = lane & 15;
    const int quad = lane >> 4;

    // LDS: 66560 + 8448 + 2048 + 128 = 77184 B  (< 160 KiB, 1 block/CU)
    __shared__ __align__(16) __bf16 wlds[2][32][JROW];  // [Wih|Whh][local col][k]
    __shared__ float gatesLds[64][33];   // [batch][32 gate cols], +1 pad col
    __shared__ float cst[64][JBLK];      // cell state fp32, block-private
    __shared__ float biasLds[32];

    // ---- weight preload: fp32 -> bf16 LDS, once per block ----
    {
        const int rr   = tid >> 2;       // 0..63
        const int mat  = rr >> 5;        // 0: Wih, 1: Whh
        const int lc   = rr & 31;        // local col: gate*8 + jj
        const int tsub = tid & 3;        // k quarter
        const int gate = lc >> 3, jj = lc & 7;
        const int grow = gate * Hh + j0 + jj;
        const float* W = mat ? Whh : Wih;
        const float* src = W + ((size_t)l * Gg + grow) * Hh + tsub * 128;
        __bf16* drow = &wlds[mat][lc][tsub * 128];
#pragma unroll
        for (int i = 0; i < 128; i += 8) {
            float4 x0 = *reinterpret_cast<const float4*>(src + i);
            float4 x1 = *reinterpret_cast<const float4*>(src + i + 4);
            pack8(x0, x1, drow + i);
        }
    }
    if (tid < 32) {
        int gate = tid >> 3, jj = tid & 7;
        int col = gate * Hh + j0 + jj;
        biasLds[tid] = bih[l * Gg + col] + bhh[l * Gg + col];
    }
    __syncthreads();

    const int brow = w * 16 + ln16;  // batch row this lane loads for A-frags
    const __bf16* wih0 = &wlds[0][ln16][0];       // tile0 cols: i(0-7), f(8-15)
    const __bf16* wih1 = &wlds[0][16 + ln16][0];  // tile1 cols: g(16-23), o(24-31)
    const __bf16* whh0 = &wlds[1][ln16][0];
    const __bf16* whh1 = &wlds[1][16 + ln16][0];

    uint32_t* ctrOwn = ctr + l * NSTEPS;
    uint32_t* ctrLo  = ctr + (l - 1) * NSTEPS;   // valid only if l>0
    uint32_t* ctrHi  = ctr + (l + 1) * NSTEPS;   // valid only if l<Ll-1

    for (int s = 0; s < NSTEPS; ++s) {
        const int t = s - l;
        const bool active = (t >= 0) && (t < Tt);

        if (active) {
            const int p = (s - 1) & 1;   // parity slot written last step
            f32x4 acc0 = {0.f, 0.f, 0.f, 0.f};
            f32x4 acc1 = {0.f, 0.f, 0.f, 0.f};

            // ---------- phase X: x_t @ Wih^T ----------
            if (l == 0) {
                const float* abase = inp + ((size_t)brow * Tt + t) * Hh;
#pragma unroll
                for (int kk = 0; kk < 16; ++kk) {
                    const int k = kk * 32 + quad * 8;
                    float4 x0 = *reinterpret_cast<const float4*>(abase + k);
                    float4 x1 = *reinterpret_cast<const float4*>(abase + k + 4);
                    bfrag a;
                    a[0] = (__bf16)x0.x; a[1] = (__bf16)x0.y;
                    a[2] = (__bf16)x0.z; a[3] = (__bf16)x0.w;
                    a[4] = (__bf16)x1.x; a[5] = (__bf16)x1.y;
                    a[6] = (__bf16)x1.z; a[7] = (__bf16)x1.w;
                    bfrag b0 = *reinterpret_cast<const bfrag*>(wih0 + k);
                    bfrag b1 = *reinterpret_cast<const bfrag*>(wih1 + k);
                    acc0 = __builtin_amdgcn_mfma_f32_16x16x32_bf16(a, b0, acc0, 0, 0, 0);
                    acc1 = __builtin_amdgcn_mfma_f32_16x16x32_bf16(a, b1, acc1, 0, 0, 0);
                }
            } else {
                const __bf16* abase = hbuf + ((size_t)((l - 1) * 2 + p) * Bb + brow) * Hh;
#pragma unroll
                for (int kk = 0; kk < 16; ++kk) {
                    const int k = kk * 32 + quad * 8;
                    bfrag a  = load_h16(abase + k);
                    bfrag b0 = *reinterpret_cast<const bfrag*>(wih0 + k);
                    bfrag b1 = *reinterpret_cast<const bfrag*>(wih1 + k);
                    acc0 = __builtin_amdgcn_mfma_f32_16x16x32_bf16(a, b0, acc0, 0, 0, 0);
                    acc1 = __builtin_amdgcn_mfma_f32_16x16x32_bf16(a, b1, acc1, 0, 0, 0);
                }
            }

            // ---------- phase H: h_{t-1} @ Whh^T ----------
            {
                const __bf16* abase = hbuf + ((size_t)(l * 2 + p) * Bb + brow) * Hh;
#pragma unroll
                for (int kk = 0; kk < 16; ++kk) {
                    const int k = kk * 32 + quad * 8;
                    bfrag a  = load_h16(abase + k);
                    bfrag b0 = *reinterpret_cast<const bfrag*>(whh0 + k);
                    bfrag b1 = *reinterpret_cast<const bfrag*>(whh1 + k);
                    acc0 = __builtin_amdgcn_mfma_f32_16x16x32_bf16(a, b0, acc0, 0, 0, 0);
                    acc1 = __builtin_amdgcn_mfma_f32_16x16x32_bf16(a, b1, acc1, 0, 0, 0);
                }
            }

            // scatter accumulators to LDS: D col=lane&15, row=quad*4+reg (m89-verified)
#pragma unroll
            for (int r = 0; r < 4; ++r) {
                gatesLds[w * 16 + quad * 4 + r][ln16]      = acc0[r];
                gatesLds[w * 16 + quad * 4 + r][16 + ln16] = acc1[r];
            }
        }
        __syncthreads();

        if (active) {
            // elementwise LSTM cell: thread -> (b = tid>>2, jj = (tid&3)*2 .. +1)
            const int b   = tid >> 2;
            const int jjb = (tid & 3) * 2;
            float hv[2], cvv[2];
#pragma unroll
            for (int u2 = 0; u2 < 2; ++u2) {
                const int jj = jjb + u2;
                float iv = gatesLds[b][jj]      + biasLds[jj];
                float fv = gatesLds[b][8 + jj]  + biasLds[8 + jj];
                float gv = gatesLds[b][16 + jj] + biasLds[16 + jj];
                float ov = gatesLds[b][24 + jj] + biasLds[24 + jj];
                float cold = (t == 0) ? 0.0f : cst[b][jj];
                float cnew = sigm(fv) * cold + sigm(iv) * tanh_(gv);
                float h = sigm(ov) * tanh_(cnew);
                cst[b][jj] = cnew;
                cvv[u2] = cnew;
                hv[u2] = h;
            }
            const int jglob = j0 + jjb;

            // publish bf16 h into this step's parity slot — WRITE-THROUGH to the
            // coherent point (sc0 sc1), so no release fence / L2 writeback is needed.
            union { __bf16 h[2]; uint32_t u; } pk;
            pk.h[0] = (__bf16)hv[0];
            pk.h[1] = (__bf16)hv[1];
            uint32_t* hdst = (uint32_t*)(hbuf + ((size_t)(l * 2 + (s & 1)) * Bb + b) * Hh + jglob);
            __hip_atomic_store(hdst, pk.u, __ATOMIC_RELAXED, __HIP_MEMORY_SCOPE_SYSTEM);

            // ---- fp32 outputs (reference dtype is float32!) ----
            if (l == Ll - 1) {   // final-layer output x[t,b,:] (time-major)
                float2 xv = make_float2(hv[0], hv[1]);
                *reinterpret_cast<float2*>(out + ((size_t)t * Bb + b) * Hh + jglob) = xv;
            }
            if (t == Tt - 1) {   // final states (hT, cT) per layer, fp32
                const size_t xend = (size_t)Tt * Bb * Hh;
                float2 hv2 = make_float2(hv[0], hv[1]);
                float2 cv2 = make_float2(cvv[0], cvv[1]);
                *reinterpret_cast<float2*>(out + xend + ((size_t)(2 * l) * Bb + b) * Hh + jglob) = hv2;
                *reinterpret_cast<float2*>(out + xend + ((size_t)(2 * l + 1) * Bb + b) * Hh + jglob) = cv2;
            }
        }

        // ---------- neighborhood sync (NO cache-maintenance fences) ----------
        // __syncthreads drains every wave's vmcnt => all write-through h stores
        // have reached the coherent point before the arrive below.
        __syncthreads();
        if (s < NSTEPS - 1) {
            if (tid == 0) {
                __hip_atomic_fetch_add(&ctrOwn[s], 1u, __ATOMIC_RELAXED, __HIP_MEMORY_SCOPE_AGENT);
                wait_ge(&ctrOwn[s], GRP);                    // own layer step s done
            } else if (tid == 64 && l > 0) {
                wait_ge(&ctrLo[s], GRP);                     // layer below done (x input)
            } else if (tid == 128 && l < Ll - 1) {
                wait_ge(&ctrHi[s], GRP);                     // layer above consumed our parity slot
            }
        }
        __syncthreads();
    }
}

extern "C" void kernel_launch(void* const* d_in, const int* in_sizes, int n_in,
                              void* d_out, int out_size, void* d_ws, size_t ws_size,
                              hipStream_t stream) {
    const float* inp = (const float*)d_in[0];
    const float* Wih = (const float*)d_in[1];
    const float* Whh = (const float*)d_in[2];
    const float* bih = (const float*)d_in[3];
    const float* bhh = (const float*)d_in[4];
    float* out = (float*)d_out;

    uint32_t* ctr  = (uint32_t*)d_ws;
    __bf16*   hbuf = (__bf16*)((char*)d_ws + CTR_BYTES);

    // zero barrier counters + h double-buffers (ws usage: ~16.5 KB + 512 KB)
    hipMemsetAsync(d_ws, 0, CTR_BYTES + HBUF_ELEMS * sizeof(__bf16), stream);

    lstm_persistent<<<dim3(NBLK), dim3(NTHR), 0, stream>>>(inp, Wih, Whh, bih, bhh,
                                                           out, ctr, hbuf);
}

// Round 2
// 10733.035 us; speedup vs baseline: 2.2318x; 1.2989x over previous
//
#include <hip/hip_runtime.h>
#include <stdint.h>
#include <stddef.h>

// ---------------- problem constants ----------------
#define Bb 64
#define Tt 1024
#define Hh 512
#define Ll 4
#define Gg 2048                 // 4*H
#define NSTEPS (Tt + Ll - 1)    // 1027 wavefront steps
#define NBLK 256                // 64 blocks per layer-group x 4 layers
#define NTHR 256                // 4 waves
#define JBLK 8                  // hidden units per block
#define JROW 520                // padded LDS weight row (bf16): 512 + 8
#define GRP 64                  // blocks per layer group
#define FLAG_STRIDE 32          // u32 per flag slot = 128 B (own cacheline)
#define FLAG_BYTES (Ll * GRP * FLAG_STRIDE * 4)        // 32 KB of epoch flags
#define HBUF_ELEMS ((size_t)Ll * 2 * Bb * Hh)          // bf16 elements

typedef __bf16 bfrag __attribute__((ext_vector_type(8)));   // 8 bf16 = 4 VGPR (MFMA A/B)
typedef float f32x4 __attribute__((ext_vector_type(4)));    // MFMA C/D
typedef uint64_t u64;

__device__ __forceinline__ float sigm(float x) { return 1.0f / (1.0f + __expf(-x)); }
__device__ __forceinline__ float tanh_(float x) {
    float ax = fabsf(x);
    float e = __expf(-2.0f * ax);
    float r = (1.0f - e) / (1.0f + e);
    return copysignf(r, x);
}

__device__ __forceinline__ void pack8(const float4& x0, const float4& x1, __bf16* dst) {
    union { __bf16 h[8]; uint4 u; } o;
    o.h[0] = (__bf16)x0.x; o.h[1] = (__bf16)x0.y;
    o.h[2] = (__bf16)x0.z; o.h[3] = (__bf16)x0.w;
    o.h[4] = (__bf16)x1.x; o.h[5] = (__bf16)x1.y;
    o.h[6] = (__bf16)x1.z; o.h[7] = (__bf16)x1.w;
    *reinterpret_cast<uint4*>(dst) = o.u;
}

// 16B h-fragment load that bypasses L1+L2 (reads the IF$/memory coherent point).
__device__ __forceinline__ bfrag load_h16(const __bf16* p) {
    union { u64 q[2]; bfrag f; } u;
    const u64* qp = reinterpret_cast<const u64*>(p);
    u.q[0] = __hip_atomic_load(qp,     __ATOMIC_RELAXED, __HIP_MEMORY_SCOPE_SYSTEM);
    u.q[1] = __hip_atomic_load(qp + 1, __ATOMIC_RELAXED, __HIP_MEMORY_SCOPE_SYSTEM);
    return u.f;
}

__device__ __forceinline__ void spin_ge(const uint32_t* p, uint32_t v) {
    while (__hip_atomic_load(p, __ATOMIC_RELAXED, __HIP_MEMORY_SCOPE_SYSTEM) < v) {
        __builtin_amdgcn_s_sleep(1);
    }
}

__global__ __launch_bounds__(NTHR, 1)
void lstm_persistent(const float* __restrict__ inp,    // [B,T,H] fp32
                     const float* __restrict__ Wih,    // [L,4H,H] fp32
                     const float* __restrict__ Whh,    // [L,4H,H] fp32
                     const float* __restrict__ bih,    // [L,4H] fp32
                     const float* __restrict__ bhh,    // [L,4H] fp32
                     float* __restrict__ out,          // fp32: [T,B,H] + L*(h,c)[B,H]
                     uint32_t* __restrict__ flags,     // [L][GRP][FLAG_STRIDE] epoch flags (zeroed)
                     __bf16* __restrict__ hbuf)        // [L][2][B][H] bf16 (zeroed)
{
    const int tid  = threadIdx.x;
    const int bx   = blockIdx.x;
    const int l    = bx >> 6;        // layer group 0..3
    const int q    = bx & 63;        // slice within group
    const int j0   = q * JBLK;       // hidden base for this block
    const int w    = tid >> 6;       // wave id == M-tile (batch rows 16w..16w+15)
    const int lane = tid & 63;
    const int ln16 = lane & 15;
    const int quad = lane >> 4;

    // LDS: 66560 + 8448 + 2048 + 128 = 77184 B  (< 160 KiB, 1 block/CU)
    __shared__ __align__(16) __bf16 wlds[2][32][JROW];  // [Wih|Whh][local col][k]
    __shared__ float gatesLds[64][33];   // [batch][32 gate cols], +1 pad col
    __shared__ float cst[64][JBLK];      // cell state fp32, block-private
    __shared__ float biasLds[32];

    // ---- weight preload: fp32 -> bf16 LDS, once per block ----
    {
        const int rr   = tid >> 2;       // 0..63
        const int mat  = rr >> 5;        // 0: Wih, 1: Whh
        const int lc   = rr & 31;        // local col: gate*8 + jj
        const int tsub = tid & 3;        // k quarter
        const int gate = lc >> 3, jj = lc & 7;
        const int grow = gate * Hh + j0 + jj;
        const float* W = mat ? Whh : Wih;
        const float* src = W + ((size_t)l * Gg + grow) * Hh + tsub * 128;
        __bf16* drow = &wlds[mat][lc][tsub * 128];
#pragma unroll
        for (int i = 0; i < 128; i += 8) {
            float4 x0 = *reinterpret_cast<const float4*>(src + i);
            float4 x1 = *reinterpret_cast<const float4*>(src + i + 4);
            pack8(x0, x1, drow + i);
        }
    }
    if (tid < 32) {
        int gate = tid >> 3, jj = tid & 7;
        int col = gate * Hh + j0 + jj;
        biasLds[tid] = bih[l * Gg + col] + bhh[l * Gg + col];
    }
    __syncthreads();

    const int brow = w * 16 + ln16;  // batch row this lane loads for A-frags
    const __bf16* wih0 = &wlds[0][ln16][0];       // tile0 cols: i(0-7), f(8-15)
    const __bf16* wih1 = &wlds[0][16 + ln16][0];  // tile1 cols: g(16-23), o(24-31)
    const __bf16* whh0 = &wlds[1][ln16][0];
    const __bf16* whh1 = &wlds[1][16 + ln16][0];

    uint32_t* flagOwn = flags + (size_t)l * GRP * FLAG_STRIDE;
    uint32_t* flagLo  = flagOwn - (size_t)GRP * FLAG_STRIDE;   // valid only if l>0
    uint32_t* flagHi  = flagOwn + (size_t)GRP * FLAG_STRIDE;   // valid only if l<Ll-1

    for (int s = 0; s < NSTEPS; ++s) {
        const int t = s - l;
        const bool active = (t >= 0) && (t < Tt);

        if (active) {
            const int p = (s - 1) & 1;   // parity slot written last step
            f32x4 acc0 = {0.f, 0.f, 0.f, 0.f};
            f32x4 acc1 = {0.f, 0.f, 0.f, 0.f};

            // ---------- phase X: x_t @ Wih^T ----------
            if (l == 0) {
                const float* abase = inp + ((size_t)brow * Tt + t) * Hh;
#pragma unroll
                for (int kk = 0; kk < 16; ++kk) {
                    const int k = kk * 32 + quad * 8;
                    float4 x0 = *reinterpret_cast<const float4*>(abase + k);
                    float4 x1 = *reinterpret_cast<const float4*>(abase + k + 4);
                    bfrag a;
                    a[0] = (__bf16)x0.x; a[1] = (__bf16)x0.y;
                    a[2] = (__bf16)x0.z; a[3] = (__bf16)x0.w;
                    a[4] = (__bf16)x1.x; a[5] = (__bf16)x1.y;
                    a[6] = (__bf16)x1.z; a[7] = (__bf16)x1.w;
                    bfrag b0 = *reinterpret_cast<const bfrag*>(wih0 + k);
                    bfrag b1 = *reinterpret_cast<const bfrag*>(wih1 + k);
                    acc0 = __builtin_amdgcn_mfma_f32_16x16x32_bf16(a, b0, acc0, 0, 0, 0);
                    acc1 = __builtin_amdgcn_mfma_f32_16x16x32_bf16(a, b1, acc1, 0, 0, 0);
                }
            } else {
                const __bf16* abase = hbuf + ((size_t)((l - 1) * 2 + p) * Bb + brow) * Hh;
#pragma unroll
                for (int kk = 0; kk < 16; ++kk) {
                    const int k = kk * 32 + quad * 8;
                    bfrag a  = load_h16(abase + k);
                    bfrag b0 = *reinterpret_cast<const bfrag*>(wih0 + k);
                    bfrag b1 = *reinterpret_cast<const bfrag*>(wih1 + k);
                    acc0 = __builtin_amdgcn_mfma_f32_16x16x32_bf16(a, b0, acc0, 0, 0, 0);
                    acc1 = __builtin_amdgcn_mfma_f32_16x16x32_bf16(a, b1, acc1, 0, 0, 0);
                }
            }

            // ---------- phase H: h_{t-1} @ Whh^T ----------
            {
                const __bf16* abase = hbuf + ((size_t)(l * 2 + p) * Bb + brow) * Hh;
#pragma unroll
                for (int kk = 0; kk < 16; ++kk) {
                    const int k = kk * 32 + quad * 8;
                    bfrag a  = load_h16(abase + k);
                    bfrag b0 = *reinterpret_cast<const bfrag*>(whh0 + k);
                    bfrag b1 = *reinterpret_cast<const bfrag*>(whh1 + k);
                    acc0 = __builtin_amdgcn_mfma_f32_16x16x32_bf16(a, b0, acc0, 0, 0, 0);
                    acc1 = __builtin_amdgcn_mfma_f32_16x16x32_bf16(a, b1, acc1, 0, 0, 0);
                }
            }

            // scatter accumulators to LDS: D col=lane&15, row=quad*4+reg (m89-verified)
#pragma unroll
            for (int r = 0; r < 4; ++r) {
                gatesLds[w * 16 + quad * 4 + r][ln16]      = acc0[r];
                gatesLds[w * 16 + quad * 4 + r][16 + ln16] = acc1[r];
            }
        }
        __syncthreads();

        if (active) {
            // elementwise LSTM cell: thread -> (b = tid>>2, jj = (tid&3)*2 .. +1)
            const int b   = tid >> 2;
            const int jjb = (tid & 3) * 2;
            float hv[2], cvv[2];
#pragma unroll
            for (int u2 = 0; u2 < 2; ++u2) {
                const int jj = jjb + u2;
                float iv = gatesLds[b][jj]      + biasLds[jj];
                float fv = gatesLds[b][8 + jj]  + biasLds[8 + jj];
                float gv = gatesLds[b][16 + jj] + biasLds[16 + jj];
                float ov = gatesLds[b][24 + jj] + biasLds[24 + jj];
                float cold = (t == 0) ? 0.0f : cst[b][jj];
                float cnew = sigm(fv) * cold + sigm(iv) * tanh_(gv);
                float h = sigm(ov) * tanh_(cnew);
                cst[b][jj] = cnew;
                cvv[u2] = cnew;
                hv[u2] = h;
            }
            const int jglob = j0 + jjb;

            // publish bf16 h into this step's parity slot — WRITE-THROUGH to the
            // coherent point (sc0 sc1), so no release fence / L2 writeback is needed.
            union { __bf16 h[2]; uint32_t u; } pk;
            pk.h[0] = (__bf16)hv[0];
            pk.h[1] = (__bf16)hv[1];
            uint32_t* hdst = (uint32_t*)(hbuf + ((size_t)(l * 2 + (s & 1)) * Bb + b) * Hh + jglob);
            __hip_atomic_store(hdst, pk.u, __ATOMIC_RELAXED, __HIP_MEMORY_SCOPE_SYSTEM);

            // ---- fp32 outputs (reference dtype is float32!) ----
            if (l == Ll - 1) {   // final-layer output x[t,b,:] (time-major)
                float2 xv = make_float2(hv[0], hv[1]);
                *reinterpret_cast<float2*>(out + ((size_t)t * Bb + b) * Hh + jglob) = xv;
            }
            if (t == Tt - 1) {   // final states (hT, cT) per layer, fp32
                const size_t xend = (size_t)Tt * Bb * Hh;
                float2 hv2 = make_float2(hv[0], hv[1]);
                float2 cv2 = make_float2(cvv[0], cvv[1]);
                *reinterpret_cast<float2*>(out + xend + ((size_t)(2 * l) * Bb + b) * Hh + jglob) = hv2;
                *reinterpret_cast<float2*>(out + xend + ((size_t)(2 * l + 1) * Bb + b) * Hh + jglob) = cv2;
            }
        }

        // ---------- neighborhood sync: contention-free epoch flags ----------
        // __syncthreads drains every wave's vmcnt => all write-through h stores
        // have reached the coherent point before the flag store below.
        __syncthreads();
        if (s < NSTEPS - 1) {
            const uint32_t want = (uint32_t)(s + 1);
            if (tid == 0) {
                // arrive: plain write-through store to our private cacheline (no RMW)
                __hip_atomic_store(&flagOwn[q * FLAG_STRIDE], want,
                                   __ATOMIC_RELAXED, __HIP_MEMORY_SCOPE_SYSTEM);
            }
            // observe: 64 lanes poll 64 flags in parallel (one round trip / iter)
            if (w == 0) {
                spin_ge(&flagOwn[lane * FLAG_STRIDE], want);       // own layer done step s
            } else if (w == 1 && l > 0) {
                spin_ge(&flagLo[lane * FLAG_STRIDE], want);        // layer below done (x input)
            } else if (w == 2 && l < Ll - 1) {
                spin_ge(&flagHi[lane * FLAG_STRIDE], want);        // layer above consumed parity slot
            }
        }
        __syncthreads();
    }
}

extern "C" void kernel_launch(void* const* d_in, const int* in_sizes, int n_in,
                              void* d_out, int out_size, void* d_ws, size_t ws_size,
                              hipStream_t stream) {
    const float* inp = (const float*)d_in[0];
    const float* Wih = (const float*)d_in[1];
    const float* Whh = (const float*)d_in[2];
    const float* bih = (const float*)d_in[3];
    const float* bhh = (const float*)d_in[4];
    float* out = (float*)d_out;

    uint32_t* flags = (uint32_t*)d_ws;
    __bf16*   hbuf  = (__bf16*)((char*)d_ws + FLAG_BYTES);

    // zero epoch flags + h double-buffers (ws usage: 32 KB + 512 KB)
    hipMemsetAsync(d_ws, 0, FLAG_BYTES + HBUF_ELEMS * sizeof(__bf16), stream);

    lstm_persistent<<<dim3(NBLK), dim3(NTHR), 0, stream>>>(inp, Wih, Whh, bih, bhh,
                                                           out, flags, hbuf);
}

// Round 5
// 10473.044 us; speedup vs baseline: 2.2872x; 1.0248x over previous
//
#include <hip/hip_runtime.h>
#include <stdint.h>
#include <stddef.h>

// ---------------- problem constants ----------------
#define Bb 64
#define Tt 1024
#define Hh 512
#define Ll 4
#define Gg 2048                 // 4*H
#define NSTEPS (Tt + Ll - 1)    // 1027 wavefront steps
#define NBLK 256                // 64 blocks per layer-group x 4 layers
#define NTHR 256                // 4 waves
#define JBLK 8                  // hidden units per block
#define JROW 520                // padded LDS weight row (bf16): 512 + 8
#define GRP 64                  // blocks per layer group
#define FLAG_STRIDE 32          // u32 per flag slot = 128 B (own cacheline)
#define FLAG_BYTES (Ll * GRP * FLAG_STRIDE * 4)        // 32 KB of epoch flags
#define HBUF_ELEMS ((size_t)Ll * 2 * Bb * Hh)          // bf16 elements

typedef __bf16 bfrag __attribute__((ext_vector_type(8)));   // 8 bf16 = 4 VGPR (MFMA A/B)
typedef float f32x4 __attribute__((ext_vector_type(4)));    // MFMA C/D
typedef uint64_t u64;

__device__ __forceinline__ float sigm(float x) { return 1.0f / (1.0f + __expf(-x)); }
__device__ __forceinline__ float tanh_(float x) {
    float ax = fabsf(x);
    float e = __expf(-2.0f * ax);
    float r = (1.0f - e) / (1.0f + e);
    return copysignf(r, x);
}

__device__ __forceinline__ void pack8(const float4& x0, const float4& x1, __bf16* dst) {
    union { __bf16 h[8]; uint4 u; } o;
    o.h[0] = (__bf16)x0.x; o.h[1] = (__bf16)x0.y;
    o.h[2] = (__bf16)x0.z; o.h[3] = (__bf16)x0.w;
    o.h[4] = (__bf16)x1.x; o.h[5] = (__bf16)x1.y;
    o.h[6] = (__bf16)x1.z; o.h[7] = (__bf16)x1.w;
    *reinterpret_cast<uint4*>(dst) = o.u;
}

// 16B h-fragment load that bypasses L1+L2 (reads the IF$/memory coherent point).
__device__ __forceinline__ bfrag load_h16(const __bf16* p) {
    union { u64 q[2]; bfrag f; } u;
    const u64* qp = reinterpret_cast<const u64*>(p);
    u.q[0] = __hip_atomic_load(qp,     __ATOMIC_RELAXED, __HIP_MEMORY_SCOPE_SYSTEM);
    u.q[1] = __hip_atomic_load(qp + 1, __ATOMIC_RELAXED, __HIP_MEMORY_SCOPE_SYSTEM);
    return u.f;
}

__device__ __forceinline__ void spin_ge(const uint32_t* p, uint32_t v) {
    while (__hip_atomic_load(p, __ATOMIC_RELAXED, __HIP_MEMORY_SCOPE_SYSTEM) < v) {
        __builtin_amdgcn_s_sleep(1);
    }
}

__global__ __launch_bounds__(NTHR, 1)
void lstm_persistent(const float* __restrict__ inp,    // [B,T,H] fp32
                     const float* __restrict__ Wih,    // [L,4H,H] fp32
                     const float* __restrict__ Whh,    // [L,4H,H] fp32
                     const float* __restrict__ bih,    // [L,4H] fp32
                     const float* __restrict__ bhh,    // [L,4H] fp32
                     float* __restrict__ out,          // fp32: [T,B,H] + L*(h,c)[B,H]
                     uint32_t* __restrict__ flags,     // [L][GRP][FLAG_STRIDE] epoch flags (zeroed)
                     __bf16* __restrict__ hbuf)        // [L][2][B][H] bf16 (zeroed)
{
    const int tid  = threadIdx.x;
    const int bx   = blockIdx.x;
    const int l    = bx >> 6;        // layer group 0..3
    const int q    = bx & 63;        // slice within group
    const int j0   = q * JBLK;       // hidden base for this block
    const int w    = tid >> 6;       // wave id == M-tile (batch rows 16w..16w+15)
    const int lane = tid & 63;
    const int ln16 = lane & 15;
    const int quad = lane >> 4;

    // LDS: 66560 + 8448 + 2048 + 128 = 77184 B  (< 160 KiB, 1 block/CU)
    __shared__ __align__(16) __bf16 wlds[2][32][JROW];  // [Wih|Whh][local col][k]
    __shared__ float gatesLds[64][33];   // [batch][32 gate cols], +1 pad col
    __shared__ float cst[64][JBLK];      // cell state fp32, block-private
    __shared__ float biasLds[32];

    // ---- weight preload: fp32 -> bf16 LDS, once per block ----
    {
        const int rr   = tid >> 2;       // 0..63
        const int mat  = rr >> 5;        // 0: Wih, 1: Whh
        const int lc   = rr & 31;        // local col: gate*8 + jj
        const int tsub = tid & 3;        // k quarter
        const int gate = lc >> 3, jj = lc & 7;
        const int grow = gate * Hh + j0 + jj;
        const float* W = mat ? Whh : Wih;
        const float* src = W + ((size_t)l * Gg + grow) * Hh + tsub * 128;
        __bf16* drow = &wlds[mat][lc][tsub * 128];
#pragma unroll
        for (int i = 0; i < 128; i += 8) {
            float4 x0 = *reinterpret_cast<const float4*>(src + i);
            float4 x1 = *reinterpret_cast<const float4*>(src + i + 4);
            pack8(x0, x1, drow + i);
        }
    }
    if (tid < 32) {
        int gate = tid >> 3, jj = tid & 7;
        int col = gate * Hh + j0 + jj;
        biasLds[tid] = bih[l * Gg + col] + bhh[l * Gg + col];
    }
    __syncthreads();

    const int brow = w * 16 + ln16;  // batch row this lane loads for A-frags
    const __bf16* wih0 = &wlds[0][ln16][0];       // tile0 cols: i(0-7), f(8-15)
    const __bf16* wih1 = &wlds[0][16 + ln16][0];  // tile1 cols: g(16-23), o(24-31)
    const __bf16* whh0 = &wlds[1][ln16][0];
    const __bf16* whh1 = &wlds[1][16 + ln16][0];

    uint32_t* flagOwn = flags + (size_t)l * GRP * FLAG_STRIDE;
    uint32_t* flagLo  = flagOwn - (size_t)GRP * FLAG_STRIDE;   // valid only if l>0
    uint32_t* flagHi  = flagOwn + (size_t)GRP * FLAG_STRIDE;   // valid only if l<Ll-1

    for (int s = 0; s < NSTEPS; ++s) {
        const int t = s - l;
        const bool active = (t >= 0) && (t < Tt);

        if (active) {
            const int p = (s - 1) & 1;   // parity slot written last step

            f32x4 aX0 = {0.f,0.f,0.f,0.f}, aX1 = {0.f,0.f,0.f,0.f};
            f32x4 aH0 = {0.f,0.f,0.f,0.f}, aH1 = {0.f,0.f,0.f,0.f};

            // ---------- phase X: batch 16 A-frags (ONE latency exposure), then MFMA ----------
            {
                bfrag ax[16];
                if (l == 0) {
                    const float* abase = inp + ((size_t)brow * Tt + t) * Hh;
#pragma unroll
                    for (int kk = 0; kk < 16; ++kk) {
                        const int k = kk * 32 + quad * 8;
                        float4 x0 = *reinterpret_cast<const float4*>(abase + k);
                        float4 x1 = *reinterpret_cast<const float4*>(abase + k + 4);
                        bfrag a;
                        a[0] = (__bf16)x0.x; a[1] = (__bf16)x0.y;
                        a[2] = (__bf16)x0.z; a[3] = (__bf16)x0.w;
                        a[4] = (__bf16)x1.x; a[5] = (__bf16)x1.y;
                        a[6] = (__bf16)x1.z; a[7] = (__bf16)x1.w;
                        ax[kk] = a;
                    }
                } else {
                    const __bf16* abase = hbuf + ((size_t)((l - 1) * 2 + p) * Bb + brow) * Hh;
#pragma unroll
                    for (int kk = 0; kk < 16; ++kk)
                        ax[kk] = load_h16(abase + kk * 32 + quad * 8);
                }
#pragma unroll
                for (int kk = 0; kk < 16; ++kk) {
                    const int k = kk * 32 + quad * 8;
                    bfrag b0 = *reinterpret_cast<const bfrag*>(wih0 + k);
                    bfrag b1 = *reinterpret_cast<const bfrag*>(wih1 + k);
                    aX0 = __builtin_amdgcn_mfma_f32_16x16x32_bf16(ax[kk], b0, aX0, 0, 0, 0);
                    aX1 = __builtin_amdgcn_mfma_f32_16x16x32_bf16(ax[kk], b1, aX1, 0, 0, 0);
                }
            }

            // ---------- phase H: batch 16 A-frags, then MFMA ----------
            {
                bfrag ah[16];
                const __bf16* hb = hbuf + ((size_t)(l * 2 + p) * Bb + brow) * Hh;
#pragma unroll
                for (int kk = 0; kk < 16; ++kk)
                    ah[kk] = load_h16(hb + kk * 32 + quad * 8);
#pragma unroll
                for (int kk = 0; kk < 16; ++kk) {
                    const int k = kk * 32 + quad * 8;
                    bfrag b0 = *reinterpret_cast<const bfrag*>(whh0 + k);
                    bfrag b1 = *reinterpret_cast<const bfrag*>(whh1 + k);
                    aH0 = __builtin_amdgcn_mfma_f32_16x16x32_bf16(ah[kk], b0, aH0, 0, 0, 0);
                    aH1 = __builtin_amdgcn_mfma_f32_16x16x32_bf16(ah[kk], b1, aH1, 0, 0, 0);
                }
            }

            f32x4 acc0 = aX0 + aH0;
            f32x4 acc1 = aX1 + aH1;

            // scatter accumulators to LDS: D col=lane&15, row=quad*4+reg (m89-verified)
#pragma unroll
            for (int r = 0; r < 4; ++r) {
                gatesLds[w * 16 + quad * 4 + r][ln16]      = acc0[r];
                gatesLds[w * 16 + quad * 4 + r][16 + ln16] = acc1[r];
            }
        }
        __syncthreads();

        if (active) {
            // elementwise LSTM cell: thread -> (b = tid>>2, jj = (tid&3)*2 .. +1)
            const int b   = tid >> 2;
            const int jjb = (tid & 3) * 2;
            float hv[2], cvv[2];
#pragma unroll
            for (int u2 = 0; u2 < 2; ++u2) {
                const int jj = jjb + u2;
                float iv = gatesLds[b][jj]      + biasLds[jj];
                float fv = gatesLds[b][8 + jj]  + biasLds[8 + jj];
                float gv = gatesLds[b][16 + jj] + biasLds[16 + jj];
                float ov = gatesLds[b][24 + jj] + biasLds[24 + jj];
                float cold = (t == 0) ? 0.0f : cst[b][jj];
                float cnew = sigm(fv) * cold + sigm(iv) * tanh_(gv);
                float h = sigm(ov) * tanh_(cnew);
                cst[b][jj] = cnew;
                cvv[u2] = cnew;
                hv[u2] = h;
            }
            const int jglob = j0 + jjb;

            // publish bf16 h into this step's parity slot — WRITE-THROUGH to the
            // coherent point (sc0 sc1), so no release fence / L2 writeback is needed.
            union { __bf16 h[2]; uint32_t u; } pk;
            pk.h[0] = (__bf16)hv[0];
            pk.h[1] = (__bf16)hv[1];
            uint32_t* hdst = (uint32_t*)(hbuf + ((size_t)(l * 2 + (s & 1)) * Bb + b) * Hh + jglob);
            __hip_atomic_store(hdst, pk.u, __ATOMIC_RELAXED, __HIP_MEMORY_SCOPE_SYSTEM);

            // ---- fp32 outputs (reference dtype is float32!) ----
            if (l == Ll - 1) {   // final-layer output x[t,b,:] (time-major)
                float2 xv = make_float2(hv[0], hv[1]);
                *reinterpret_cast<float2*>(out + ((size_t)t * Bb + b) * Hh + jglob) = xv;
            }
            if (t == Tt - 1) {   // final states (hT, cT) per layer, fp32
                const size_t xend = (size_t)Tt * Bb * Hh;
                float2 hv2 = make_float2(hv[0], hv[1]);
                float2 cv2 = make_float2(cvv[0], cvv[1]);
                *reinterpret_cast<float2*>(out + xend + ((size_t)(2 * l) * Bb + b) * Hh + jglob) = hv2;
                *reinterpret_cast<float2*>(out + xend + ((size_t)(2 * l + 1) * Bb + b) * Hh + jglob) = cv2;
            }
        }

        // ---------- neighborhood sync: contention-free epoch flags ----------
        // __syncthreads drains every wave's vmcnt => all write-through h stores
        // have reached the coherent point before the flag store below.
        __syncthreads();
        if (s < NSTEPS - 1) {
            const uint32_t want = (uint32_t)(s + 1);
            if (tid == 0) {
                // arrive: plain write-through store to our private cacheline (no RMW)
                __hip_atomic_store(&flagOwn[q * FLAG_STRIDE], want,
                                   __ATOMIC_RELAXED, __HIP_MEMORY_SCOPE_SYSTEM);
            }
            // observe: 64 lanes poll 64 flags in parallel (one round trip / iter)
            if (w == 0) {
                spin_ge(&flagOwn[lane * FLAG_STRIDE], want);       // own layer done step s
            } else if (w == 1 && l > 0) {
                spin_ge(&flagLo[lane * FLAG_STRIDE], want);        // layer below done (x input)
            } else if (w == 2 && l < Ll - 1) {
                spin_ge(&flagHi[lane * FLAG_STRIDE], want);        // layer above consumed parity slot
            }
            // compiler-only fence: forbid hoisting next step's h loads above the spin
            asm volatile("" ::: "memory");
        }
        __syncthreads();
    }
}

extern "C" void kernel_launch(void* const* d_in, const int* in_sizes, int n_in,
                              void* d_out, int out_size, void* d_ws, size_t ws_size,
                              hipStream_t stream) {
    const float* inp = (const float*)d_in[0];
    const float* Wih = (const float*)d_in[1];
    const float* Whh = (const float*)d_in[2];
    const float* bih = (const float*)d_in[3];
    const float* bhh = (const float*)d_in[4];
    float* out = (float*)d_out;

    uint32_t* flags = (uint32_t*)d_ws;
    __bf16*   hbuf  = (__bf16*)((char*)d_ws + FLAG_BYTES);

    // zero epoch flags + h double-buffers (ws usage: 32 KB + 512 KB)
    hipMemsetAsync(d_ws, 0, FLAG_BYTES + HBUF_ELEMS * sizeof(__bf16), stream);

    lstm_persistent<<<dim3(NBLK), dim3(NTHR), 0, stream>>>(inp, Wih, Whh, bih, bhh,
                                                           out, flags, hbuf);
}

// Round 6
// 9502.384 us; speedup vs baseline: 2.5209x; 1.1021x over previous
//
#include <hip/hip_runtime.h>
#include <stdint.h>
#include <stddef.h>

// ---------------- problem constants ----------------
#define Bb 64
#define Tt 1024
#define Hh 512
#define Ll 4
#define Gg 2048                 // 4*H
#define NSTEPS (Tt + Ll - 1)    // 1027 wavefront steps
#define NBLK 256                // 64 blocks per layer-group x 4 layers
#define NTHR 256                // 4 waves
#define JBLK 8                  // hidden units per block
#define JROW 520                // padded LDS weight row (bf16): 512 + 8
#define GRP 64                  // blocks per layer group
#define FLAG_STRIDE 32          // u32 per flag slot = 128 B (own cacheline)
#define FLAG_BYTES (Ll * GRP * FLAG_STRIDE * 4)        // 32 KB of epoch flags
#define HBUF_ELEMS ((size_t)Ll * 2 * Bb * Hh)          // bf16 elements

typedef __bf16 bfrag __attribute__((ext_vector_type(8)));   // 8 bf16 = 4 VGPR (MFMA A/B)
typedef float f32x4 __attribute__((ext_vector_type(4)));    // MFMA C/D
typedef uint64_t u64;

__device__ __forceinline__ float sigm(float x) { return 1.0f / (1.0f + __expf(-x)); }
__device__ __forceinline__ float tanh_(float x) {
    float ax = fabsf(x);
    float e = __expf(-2.0f * ax);
    float r = (1.0f - e) / (1.0f + e);
    return copysignf(r, x);
}

__device__ __forceinline__ void pack8(const float4& x0, const float4& x1, __bf16* dst) {
    union { __bf16 h[8]; uint4 u; } o;
    o.h[0] = (__bf16)x0.x; o.h[1] = (__bf16)x0.y;
    o.h[2] = (__bf16)x0.z; o.h[3] = (__bf16)x0.w;
    o.h[4] = (__bf16)x1.x; o.h[5] = (__bf16)x1.y;
    o.h[6] = (__bf16)x1.z; o.h[7] = (__bf16)x1.w;
    *reinterpret_cast<uint4*>(dst) = o.u;
}

// Issue one 16B uncached (coherent-point) load WITHOUT waiting. asm output
// forces the destination registers live -> compiler cannot re-serialize.
// sc0 sc1 = bypass L1+L2, read MALL (same semantics as relaxed system atomic).
__device__ __forceinline__ bfrag load_h16_async(const __bf16* p) {
    bfrag r;
    asm volatile("global_load_dwordx4 %0, %1, off sc0 sc1"
                 : "=v"(r) : "v"(p));
    return r;
}

// Throttled spin: first check immediately; back off ~213ns between re-polls
// to keep 256 blocks' polling from saturating the coherent fabric.
__device__ __forceinline__ void spin_ge(const uint32_t* p, uint32_t v) {
    if (__hip_atomic_load(p, __ATOMIC_RELAXED, __HIP_MEMORY_SCOPE_SYSTEM) >= v) return;
    for (;;) {
        __builtin_amdgcn_s_sleep(8);
        if (__hip_atomic_load(p, __ATOMIC_RELAXED, __HIP_MEMORY_SCOPE_SYSTEM) >= v) return;
    }
}

__global__ __launch_bounds__(NTHR, 1)
void lstm_persistent(const float* __restrict__ inp,    // [B,T,H] fp32
                     const float* __restrict__ Wih,    // [L,4H,H] fp32
                     const float* __restrict__ Whh,    // [L,4H,H] fp32
                     const float* __restrict__ bih,    // [L,4H] fp32
                     const float* __restrict__ bhh,    // [L,4H] fp32
                     float* __restrict__ out,          // fp32: [T,B,H] + L*(h,c)[B,H]
                     uint32_t* __restrict__ flags,     // [L][GRP][FLAG_STRIDE] epoch flags (zeroed)
                     __bf16* __restrict__ hbuf)        // [L][2][B][H] bf16 (zeroed)
{
    const int tid  = threadIdx.x;
    const int bx   = blockIdx.x;
    const int l    = bx >> 6;        // layer group 0..3
    const int q    = bx & 63;        // slice within group
    const int j0   = q * JBLK;       // hidden base for this block
    const int w    = tid >> 6;       // wave id == M-tile (batch rows 16w..16w+15)
    const int lane = tid & 63;
    const int ln16 = lane & 15;
    const int quad = lane >> 4;

    // LDS: 66560 + 8448 + 2048 + 128 = 77184 B  (< 160 KiB, 1 block/CU)
    __shared__ __align__(16) __bf16 wlds[2][32][JROW];  // [Wih|Whh][local col][k]
    __shared__ float gatesLds[64][33];   // [batch][32 gate cols], +1 pad col
    __shared__ float cst[64][JBLK];      // cell state fp32, block-private
    __shared__ float biasLds[32];

    // ---- weight preload: fp32 -> bf16 LDS, once per block ----
    {
        const int rr   = tid >> 2;       // 0..63
        const int mat  = rr >> 5;        // 0: Wih, 1: Whh
        const int lc   = rr & 31;        // local col: gate*8 + jj
        const int tsub = tid & 3;        // k quarter
        const int gate = lc >> 3, jj = lc & 7;
        const int grow = gate * Hh + j0 + jj;
        const float* W = mat ? Whh : Wih;
        const float* src = W + ((size_t)l * Gg + grow) * Hh + tsub * 128;
        __bf16* drow = &wlds[mat][lc][tsub * 128];
#pragma unroll
        for (int i = 0; i < 128; i += 8) {
            float4 x0 = *reinterpret_cast<const float4*>(src + i);
            float4 x1 = *reinterpret_cast<const float4*>(src + i + 4);
            pack8(x0, x1, drow + i);
        }
    }
    if (tid < 32) {
        int gate = tid >> 3, jj = tid & 7;
        int col = gate * Hh + j0 + jj;
        biasLds[tid] = bih[l * Gg + col] + bhh[l * Gg + col];
    }
    __syncthreads();

    const int brow = w * 16 + ln16;  // batch row this lane loads for A-frags
    const __bf16* wih0 = &wlds[0][ln16][0];       // tile0 cols: i(0-7), f(8-15)
    const __bf16* wih1 = &wlds[0][16 + ln16][0];  // tile1 cols: g(16-23), o(24-31)
    const __bf16* whh0 = &wlds[1][ln16][0];
    const __bf16* whh1 = &wlds[1][16 + ln16][0];

    uint32_t* flagOwn = flags + (size_t)l * GRP * FLAG_STRIDE;
    uint32_t* flagLo  = flagOwn - (size_t)GRP * FLAG_STRIDE;   // valid only if l>0
    uint32_t* flagHi  = flagOwn + (size_t)GRP * FLAG_STRIDE;   // valid only if l<Ll-1

    for (int s = 0; s < NSTEPS; ++s) {
        const int t = s - l;
        const bool active = (t >= 0) && (t < Tt);

        if (active) {
            const int p = (s - 1) & 1;   // parity slot written last step

            f32x4 aX0 = {0.f,0.f,0.f,0.f}, aX1 = {0.f,0.f,0.f,0.f};
            f32x4 aH0 = {0.f,0.f,0.f,0.f}, aH1 = {0.f,0.f,0.f,0.f};

            // ---------- phase X: 16 asm loads in flight -> ONE wait -> MFMA ----------
            {
                bfrag ax[16];
                if (l == 0) {
                    const float* abase = inp + ((size_t)brow * Tt + t) * Hh;
#pragma unroll
                    for (int kk = 0; kk < 16; ++kk) {
                        const int k = kk * 32 + quad * 8;
                        float4 x0 = *reinterpret_cast<const float4*>(abase + k);
                        float4 x1 = *reinterpret_cast<const float4*>(abase + k + 4);
                        bfrag a;
                        a[0] = (__bf16)x0.x; a[1] = (__bf16)x0.y;
                        a[2] = (__bf16)x0.z; a[3] = (__bf16)x0.w;
                        a[4] = (__bf16)x1.x; a[5] = (__bf16)x1.y;
                        a[6] = (__bf16)x1.z; a[7] = (__bf16)x1.w;
                        ax[kk] = a;
                    }
                } else {
                    const __bf16* abase = hbuf + ((size_t)((l - 1) * 2 + p) * Bb + brow) * Hh;
#pragma unroll
                    for (int kk = 0; kk < 16; ++kk)
                        ax[kk] = load_h16_async(abase + kk * 32 + quad * 8);
                    asm volatile("s_waitcnt vmcnt(0)" ::: "memory");
                    __builtin_amdgcn_sched_barrier(0);   // rule #18: no MFMA hoist above wait
                }
#pragma unroll
                for (int kk = 0; kk < 16; ++kk) {
                    const int k = kk * 32 + quad * 8;
                    bfrag b0 = *reinterpret_cast<const bfrag*>(wih0 + k);
                    bfrag b1 = *reinterpret_cast<const bfrag*>(wih1 + k);
                    aX0 = __builtin_amdgcn_mfma_f32_16x16x32_bf16(ax[kk], b0, aX0, 0, 0, 0);
                    aX1 = __builtin_amdgcn_mfma_f32_16x16x32_bf16(ax[kk], b1, aX1, 0, 0, 0);
                }
            }

            // ---------- phase H: 16 asm loads in flight -> ONE wait -> MFMA ----------
            {
                bfrag ah[16];
                const __bf16* hb = hbuf + ((size_t)(l * 2 + p) * Bb + brow) * Hh;
#pragma unroll
                for (int kk = 0; kk < 16; ++kk)
                    ah[kk] = load_h16_async(hb + kk * 32 + quad * 8);
                asm volatile("s_waitcnt vmcnt(0)" ::: "memory");
                __builtin_amdgcn_sched_barrier(0);       // rule #18
#pragma unroll
                for (int kk = 0; kk < 16; ++kk) {
                    const int k = kk * 32 + quad * 8;
                    bfrag b0 = *reinterpret_cast<const bfrag*>(whh0 + k);
                    bfrag b1 = *reinterpret_cast<const bfrag*>(whh1 + k);
                    aH0 = __builtin_amdgcn_mfma_f32_16x16x32_bf16(ah[kk], b0, aH0, 0, 0, 0);
                    aH1 = __builtin_amdgcn_mfma_f32_16x16x32_bf16(ah[kk], b1, aH1, 0, 0, 0);
                }
            }

            f32x4 acc0 = aX0 + aH0;
            f32x4 acc1 = aX1 + aH1;

            // scatter accumulators to LDS: D col=lane&15, row=quad*4+reg (m89-verified)
#pragma unroll
            for (int r = 0; r < 4; ++r) {
                gatesLds[w * 16 + quad * 4 + r][ln16]      = acc0[r];
                gatesLds[w * 16 + quad * 4 + r][16 + ln16] = acc1[r];
            }
        }
        __syncthreads();

        if (active) {
            // elementwise LSTM cell: thread -> (b = tid>>2, jj = (tid&3)*2 .. +1)
            const int b   = tid >> 2;
            const int jjb = (tid & 3) * 2;
            float hv[2], cvv[2];
#pragma unroll
            for (int u2 = 0; u2 < 2; ++u2) {
                const int jj = jjb + u2;
                float iv = gatesLds[b][jj]      + biasLds[jj];
                float fv = gatesLds[b][8 + jj]  + biasLds[8 + jj];
                float gv = gatesLds[b][16 + jj] + biasLds[16 + jj];
                float ov = gatesLds[b][24 + jj] + biasLds[24 + jj];
                float cold = (t == 0) ? 0.0f : cst[b][jj];
                float cnew = sigm(fv) * cold + sigm(iv) * tanh_(gv);
                float h = sigm(ov) * tanh_(cnew);
                cst[b][jj] = cnew;
                cvv[u2] = cnew;
                hv[u2] = h;
            }
            const int jglob = j0 + jjb;

            // publish bf16 h into this step's parity slot — WRITE-THROUGH to the
            // coherent point (sc0 sc1), so no release fence / L2 writeback is needed.
            union { __bf16 h[2]; uint32_t u; } pk;
            pk.h[0] = (__bf16)hv[0];
            pk.h[1] = (__bf16)hv[1];
            uint32_t* hdst = (uint32_t*)(hbuf + ((size_t)(l * 2 + (s & 1)) * Bb + b) * Hh + jglob);
            __hip_atomic_store(hdst, pk.u, __ATOMIC_RELAXED, __HIP_MEMORY_SCOPE_SYSTEM);

            // ---- fp32 outputs (reference dtype is float32!) ----
            if (l == Ll - 1) {   // final-layer output x[t,b,:] (time-major)
                float2 xv = make_float2(hv[0], hv[1]);
                *reinterpret_cast<float2*>(out + ((size_t)t * Bb + b) * Hh + jglob) = xv;
            }
            if (t == Tt - 1) {   // final states (hT, cT) per layer, fp32
                const size_t xend = (size_t)Tt * Bb * Hh;
                float2 hv2 = make_float2(hv[0], hv[1]);
                float2 cv2 = make_float2(cvv[0], cvv[1]);
                *reinterpret_cast<float2*>(out + xend + ((size_t)(2 * l) * Bb + b) * Hh + jglob) = hv2;
                *reinterpret_cast<float2*>(out + xend + ((size_t)(2 * l + 1) * Bb + b) * Hh + jglob) = cv2;
            }
        }

        // ---------- neighborhood sync: contention-free epoch flags ----------
        // __syncthreads drains every wave's vmcnt => all write-through h stores
        // have reached the coherent point before the flag store below.
        __syncthreads();
        if (s < NSTEPS - 1) {
            const uint32_t want = (uint32_t)(s + 1);
            if (tid == 0) {
                // arrive: plain write-through store to our private cacheline (no RMW)
                __hip_atomic_store(&flagOwn[q * FLAG_STRIDE], want,
                                   __ATOMIC_RELAXED, __HIP_MEMORY_SCOPE_SYSTEM);
            }
            // observe: 64 lanes poll 64 flags in parallel (throttled re-poll)
            if (w == 0) {
                spin_ge(&flagOwn[lane * FLAG_STRIDE], want);       // own layer done step s
            } else if (w == 1 && l > 0) {
                spin_ge(&flagLo[lane * FLAG_STRIDE], want);        // layer below done (x input)
            } else if (w == 2 && l < Ll - 1) {
                spin_ge(&flagHi[lane * FLAG_STRIDE], want);        // layer above consumed parity slot
            }
            // compiler-only fence: forbid hoisting next step's h loads above the spin
            asm volatile("" ::: "memory");
        }
        __syncthreads();
    }
}

extern "C" void kernel_launch(void* const* d_in, const int* in_sizes, int n_in,
                              void* d_out, int out_size, void* d_ws, size_t ws_size,
                              hipStream_t stream) {
    const float* inp = (const float*)d_in[0];
    const float* Wih = (const float*)d_in[1];
    const float* Whh = (const float*)d_in[2];
    const float* bih = (const float*)d_in[3];
    const float* bhh = (const float*)d_in[4];
    float* out = (float*)d_out;

    uint32_t* flags = (uint32_t*)d_ws;
    __bf16*   hbuf  = (__bf16*)((char*)d_ws + FLAG_BYTES);

    // zero epoch flags + h double-buffers (ws usage: 32 KB + 512 KB)
    hipMemsetAsync(d_ws, 0, FLAG_BYTES + HBUF_ELEMS * sizeof(__bf16), stream);

    lstm_persistent<<<dim3(NBLK), dim3(NTHR), 0, stream>>>(inp, Wih, Whh, bih, bhh,
                                                           out, flags, hbuf);
}

// Round 7
// 5803.052 us; speedup vs baseline: 4.1279x; 1.6375x over previous
//
#include <hip/hip_runtime.h>
#include <stdint.h>
#include <stddef.h>

// ---------------- problem constants ----------------
#define Bb 64
#define Tt 1024
#define Hh 512
#define Ll 4
#define Gg 2048                 // 4*H
#define NSTEPS (Tt + Ll - 1)    // 1027 wavefront steps
#define NBLK 256                // 4 layers x 4 batch-slices x 16 j-slices
#define NTHR 256                // 4 waves
#define GRP 64                  // blocks per layer group
#define FLAG_STRIDE 32          // u32 per flag slot = 128 B (own cacheline)
#define FLAG_BYTES (Ll * GRP * FLAG_STRIDE * 4)        // 32 KB of epoch flags
#define HBUF_ELEMS ((size_t)Ll * 2 * Bb * Hh)          // bf16 elements
#define HPAD 520                // padded LDS A-row: 512 bf16 + 8
#define HROWB (HPAD * 2)        // 1040 bytes per LDS A-row

typedef __bf16 bfrag __attribute__((ext_vector_type(8)));   // 8 bf16 = 4 VGPR (MFMA A/B)
typedef float f32x4 __attribute__((ext_vector_type(4)));    // MFMA C/D
typedef uint64_t u64;

__device__ __forceinline__ float sigm(float x) { return 1.0f / (1.0f + __expf(-x)); }
__device__ __forceinline__ float tanh_(float x) {
    float ax = fabsf(x);
    float e = __expf(-2.0f * ax);
    float r = (1.0f - e) / (1.0f + e);
    return copysignf(r, x);
}

__device__ __forceinline__ bfrag cvt8(const float4& x0, const float4& x1) {
    bfrag a;
    a[0] = (__bf16)x0.x; a[1] = (__bf16)x0.y; a[2] = (__bf16)x0.z; a[3] = (__bf16)x0.w;
    a[4] = (__bf16)x1.x; a[5] = (__bf16)x1.y; a[6] = (__bf16)x1.z; a[7] = (__bf16)x1.w;
    return a;
}

__device__ __forceinline__ void pack8(const float4& x0, const float4& x1, __bf16* dst) {
    union { __bf16 h[8]; uint4 u; } o;
    o.h[0] = (__bf16)x0.x; o.h[1] = (__bf16)x0.y;
    o.h[2] = (__bf16)x0.z; o.h[3] = (__bf16)x0.w;
    o.h[4] = (__bf16)x1.x; o.h[5] = (__bf16)x1.y;
    o.h[6] = (__bf16)x1.z; o.h[7] = (__bf16)x1.w;
    *reinterpret_cast<uint4*>(dst) = o.u;
}

// Issue one 16B uncached (coherent-point) load WITHOUT waiting.
__device__ __forceinline__ bfrag load_h16_async(const __bf16* p) {
    bfrag r;
    asm volatile("global_load_dwordx4 %0, %1, off sc0 sc1"
                 : "=v"(r) : "v"(p));
    return r;
}

// Throttled spin (verified r6 structure).
__device__ __forceinline__ void spin_ge(const uint32_t* p, uint32_t v) {
    if (__hip_atomic_load(p, __ATOMIC_RELAXED, __HIP_MEMORY_SCOPE_SYSTEM) >= v) return;
    for (;;) {
        __builtin_amdgcn_s_sleep(8);
        if (__hip_atomic_load(p, __ATOMIC_RELAXED, __HIP_MEMORY_SCOPE_SYSTEM) >= v) return;
    }
}

__global__ __launch_bounds__(NTHR, 1)
void lstm_persistent(const float* __restrict__ inp,    // [B,T,H] fp32
                     const float* __restrict__ Wih,    // [L,4H,H] fp32
                     const float* __restrict__ Whh,    // [L,4H,H] fp32
                     const float* __restrict__ bih,    // [L,4H] fp32
                     const float* __restrict__ bhh,    // [L,4H] fp32
                     float* __restrict__ out,          // fp32: [T,B,H] + L*(h,c)[B,H]
                     uint32_t* __restrict__ flags,     // [L][GRP][FLAG_STRIDE] epoch flags (zeroed)
                     __bf16* __restrict__ hbuf)        // [L][2][B][H] bf16 (zeroed)
{
    const int tid  = threadIdx.x;
    const int bx   = blockIdx.x;
    const int l    = bx >> 6;        // layer 0..3
    const int rem  = bx & 63;
    const int r    = rem >> 4;       // batch-slice 0..3 (rows 16r..16r+15)
    const int qj   = rem & 15;       // j-slice 0..15 (hidden cols qj*32..+31)
    const int J0   = qj * 32;
    const int w    = tid >> 6;       // wave id: owns j-sub-slice 8w..8w+7 (x 4 gates)
    const int lane = tid & 63;
    const int ln16 = lane & 15;
    const int quad = lane >> 4;

    // LDS: 33280 (A-tiles) + 8448 (gates) + 2048 (cst) + 512 (bias) = 44288 B
    __shared__ __align__(16) __bf16 hA2[2][16][HPAD];  // [X|H][row][k], XOR-swizzled
    __shared__ float gatesLds[16][132];  // [row][block gate col], wave-private slabs
    __shared__ float cst[16][32];        // cell state, wave-private cols
    __shared__ float biasLds[4][32];     // [wave][lc]

    // ---- weight preload: fp32 global -> bf16 B-fragments in REGISTERS ----
    // wave w, tile tl, lane col ln16 -> lc = tl*16+ln16, gate = lc>>3, jj = lc&7
    bfrag wih_r[2][16], whh_r[2][16];
#pragma unroll
    for (int tl = 0; tl < 2; ++tl) {
        const int lc   = tl * 16 + ln16;
        const int gate = lc >> 3, jj = lc & 7;
        const int gcol = gate * Hh + J0 + 8 * w + jj;
        const float* wiRow = Wih + ((size_t)l * Gg + gcol) * Hh;
        const float* whRow = Whh + ((size_t)l * Gg + gcol) * Hh;
#pragma unroll
        for (int kk = 0; kk < 16; ++kk) {
            const int k = kk * 32 + quad * 8;
            float4 x0 = *reinterpret_cast<const float4*>(wiRow + k);
            float4 x1 = *reinterpret_cast<const float4*>(wiRow + k + 4);
            wih_r[tl][kk] = cvt8(x0, x1);
            float4 y0 = *reinterpret_cast<const float4*>(whRow + k);
            float4 y1 = *reinterpret_cast<const float4*>(whRow + k + 4);
            whh_r[tl][kk] = cvt8(y0, y1);
        }
    }
    if (tid < 128) {
        const int ww = tid >> 5, lc = tid & 31;
        const int gate = lc >> 3, jj = lc & 7;
        const int col = gate * Hh + J0 + 8 * ww + jj;
        biasLds[ww][lc] = bih[l * Gg + col] + bhh[l * Gg + col];
    }
    __syncthreads();

    uint32_t* flagOwn = flags + (size_t)l * GRP * FLAG_STRIDE;
    uint32_t* flagLo  = flagOwn - (size_t)GRP * FLAG_STRIDE;   // valid only if l>0
    uint32_t* flagHi  = flagOwn + (size_t)GRP * FLAG_STRIDE;   // valid only if l<Ll-1

    // cell mapping (wave-private): lane -> (row bl4, j-pair jjb within wave's 8)
    const int bl4   = lane >> 2;         // 0..15
    const int jjb   = (lane & 3) * 2;    // 0,2,4,6
    const int bglob = 16 * r + bl4;
    const int sw    = (ln16 & 7) << 4;   // A-read XOR swizzle for this lane

    for (int s = 0; s < NSTEPS; ++s) {
        const int t = s - l;
        const bool active = (t >= 0) && (t < Tt);

        if (active) {
            const int p = (s - 1) & 1;   // parity slot written last step

            // ---------- cooperative staging: block's 16 A-rows, both phases ----------
            // 1024 chunks of 16B per phase; thread covers chunks tid+256*i (coalesced).
            if (l == 0) {
                bfrag hv4[4];
#pragma unroll
                for (int i = 0; i < 4; ++i) {   // issue uncached H loads first
                    const int c = tid + 256 * i;
                    const int row = c >> 6, k16 = c & 63;
                    hv4[i] = load_h16_async(hbuf + ((size_t)(l * 2 + p) * Bb + 16 * r + row) * Hh + k16 * 8);
                }
#pragma unroll
                for (int i = 0; i < 4; ++i) {   // X from inp (cached fp32), convert
                    const int c = tid + 256 * i;
                    const int row = c >> 6, k16 = c & 63;
                    const float* src = inp + ((size_t)(16 * r + row) * Tt + t) * Hh + k16 * 8;
                    float4 x0 = *reinterpret_cast<const float4*>(src);
                    float4 x1 = *reinterpret_cast<const float4*>(src + 4);
                    char* dp = (char*)&hA2[0][0][0] + row * HROWB + ((k16 * 16) ^ ((row & 7) << 4));
                    pack8(x0, x1, (__bf16*)dp);
                }
                asm volatile("s_waitcnt vmcnt(0)" ::: "memory");
#pragma unroll
                for (int i = 0; i < 4; ++i) {
                    const int c = tid + 256 * i;
                    const int row = c >> 6, k16 = c & 63;
                    char* dp = (char*)&hA2[1][0][0] + row * HROWB + ((k16 * 16) ^ ((row & 7) << 4));
                    union { bfrag f; uint4 u; } cv; cv.f = hv4[i];
                    *reinterpret_cast<uint4*>(dp) = cv.u;
                }
            } else {
                bfrag xv4[4], hv4[4];
#pragma unroll
                for (int i = 0; i < 4; ++i) {   // issue ALL 8 uncached loads: one exposure
                    const int c = tid + 256 * i;
                    const int row = c >> 6, k16 = c & 63;
                    xv4[i] = load_h16_async(hbuf + ((size_t)((l - 1) * 2 + p) * Bb + 16 * r + row) * Hh + k16 * 8);
                    hv4[i] = load_h16_async(hbuf + ((size_t)(l * 2 + p) * Bb + 16 * r + row) * Hh + k16 * 8);
                }
                asm volatile("s_waitcnt vmcnt(0)" ::: "memory");
#pragma unroll
                for (int i = 0; i < 4; ++i) {
                    const int c = tid + 256 * i;
                    const int row = c >> 6, k16 = c & 63;
                    const int so = ((k16 * 16) ^ ((row & 7) << 4));
                    union { bfrag f; uint4 u; } cx; cx.f = xv4[i];
                    union { bfrag f; uint4 u; } ch; ch.f = hv4[i];
                    *reinterpret_cast<uint4*>((char*)&hA2[0][0][0] + row * HROWB + so) = cx.u;
                    *reinterpret_cast<uint4*>((char*)&hA2[1][0][0] + row * HROWB + so) = ch.u;
                }
            }
            __syncthreads();   // staging visible to all waves

            // ---------- MFMA: A from LDS (swizzled), B from registers ----------
            f32x4 acc0 = {0.f, 0.f, 0.f, 0.f};
            f32x4 acc1 = {0.f, 0.f, 0.f, 0.f};
            const char* aXp = (const char*)&hA2[0][0][0] + ln16 * HROWB;
            const char* aHp = (const char*)&hA2[1][0][0] + ln16 * HROWB;
#pragma unroll
            for (int kk = 0; kk < 16; ++kk) {
                const int off = (kk * 64 + quad * 16) ^ sw;
                bfrag aX = *reinterpret_cast<const bfrag*>(aXp + off);
                bfrag aH = *reinterpret_cast<const bfrag*>(aHp + off);
                acc0 = __builtin_amdgcn_mfma_f32_16x16x32_bf16(aX, wih_r[0][kk], acc0, 0, 0, 0);
                acc1 = __builtin_amdgcn_mfma_f32_16x16x32_bf16(aX, wih_r[1][kk], acc1, 0, 0, 0);
                acc0 = __builtin_amdgcn_mfma_f32_16x16x32_bf16(aH, whh_r[0][kk], acc0, 0, 0, 0);
                acc1 = __builtin_amdgcn_mfma_f32_16x16x32_bf16(aH, whh_r[1][kk], acc1, 0, 0, 0);
            }

            // scatter to wave-private gate slab: D col=lane&15, row=quad*4+reg
#pragma unroll
            for (int rr2 = 0; rr2 < 4; ++rr2) {
                gatesLds[quad * 4 + rr2][32 * w + ln16]      = acc0[rr2];
                gatesLds[32 * w + 16 + ln16 >= 0 ? quad * 4 + rr2 : 0][32 * w + 16 + ln16] = acc1[rr2];
            }
            // same-wave LDS dependency: make the scatter visible before cell reads
            asm volatile("s_waitcnt lgkmcnt(0)" ::: "memory");
            __builtin_amdgcn_sched_barrier(0);

            // ---------- elementwise LSTM cell (wave-private) ----------
            float hvv[2], cvv[2];
#pragma unroll
            for (int u2 = 0; u2 < 2; ++u2) {
                const int jj = jjb + u2;
                float iv = gatesLds[bl4][32 * w + jj]      + biasLds[w][jj];
                float fv = gatesLds[bl4][32 * w + 8 + jj]  + biasLds[w][8 + jj];
                float gv = gatesLds[bl4][32 * w + 16 + jj] + biasLds[w][16 + jj];
                float ov = gatesLds[bl4][32 * w + 24 + jj] + biasLds[w][24 + jj];
                float cold = (t == 0) ? 0.0f : cst[bl4][8 * w + jj];
                float cnew = sigm(fv) * cold + sigm(iv) * tanh_(gv);
                float h = sigm(ov) * tanh_(cnew);
                cst[bl4][8 * w + jj] = cnew;
                cvv[u2] = cnew;
                hvv[u2] = h;
            }
            const int hcol = J0 + 8 * w + jjb;

            // publish bf16 h (write-through to coherent point)
            union { __bf16 h[2]; uint32_t u; } pk;
            pk.h[0] = (__bf16)hvv[0];
            pk.h[1] = (__bf16)hvv[1];
            uint32_t* hdst = (uint32_t*)(hbuf + ((size_t)(l * 2 + (s & 1)) * Bb + bglob) * Hh + hcol);
            __hip_atomic_store(hdst, pk.u, __ATOMIC_RELAXED, __HIP_MEMORY_SCOPE_SYSTEM);

            // ---- fp32 outputs ----
            if (l == Ll - 1) {
                float2 xv = make_float2(hvv[0], hvv[1]);
                *reinterpret_cast<float2*>(out + ((size_t)t * Bb + bglob) * Hh + hcol) = xv;
            }
            if (t == Tt - 1) {
                const size_t xend = (size_t)Tt * Bb * Hh;
                float2 hv2 = make_float2(hvv[0], hvv[1]);
                float2 cv2 = make_float2(cvv[0], cvv[1]);
                *reinterpret_cast<float2*>(out + xend + ((size_t)(2 * l) * Bb + bglob) * Hh + hcol) = hv2;
                *reinterpret_cast<float2*>(out + xend + ((size_t)(2 * l + 1) * Bb + bglob) * Hh + hcol) = cv2;
            }
        }

        // ---------- neighborhood sync: verified r2/r6 structure, unchanged ----------
        __syncthreads();
        if (s < NSTEPS - 1) {
            const uint32_t want = (uint32_t)(s + 1);
            if (tid == 0) {
                __hip_atomic_store(&flagOwn[(rem)*FLAG_STRIDE], want,
                                   __ATOMIC_RELAXED, __HIP_MEMORY_SCOPE_SYSTEM);
            }
            if (w == 0) {
                spin_ge(&flagOwn[lane * FLAG_STRIDE], want);       // own layer done step s
            } else if (w == 1 && l > 0) {
                spin_ge(&flagLo[lane * FLAG_STRIDE], want);        // layer below done (x input)
            } else if (w == 2 && l < Ll - 1) {
                spin_ge(&flagHi[lane * FLAG_STRIDE], want);        // layer above consumed parity slot
            }
            asm volatile("" ::: "memory");
        }
        __syncthreads();
    }
}

extern "C" void kernel_launch(void* const* d_in, const int* in_sizes, int n_in,
                              void* d_out, int out_size, void* d_ws, size_t ws_size,
                              hipStream_t stream) {
    const float* inp = (const float*)d_in[0];
    const float* Wih = (const float*)d_in[1];
    const float* Whh = (const float*)d_in[2];
    const float* bih = (const float*)d_in[3];
    const float* bhh = (const float*)d_in[4];
    float* out = (float*)d_out;

    uint32_t* flags = (uint32_t*)d_ws;
    __bf16*   hbuf  = (__bf16*)((char*)d_ws + FLAG_BYTES);

    // zero epoch flags + h double-buffers (ws usage: 32 KB + 512 KB)
    hipMemsetAsync(d_ws, 0, FLAG_BYTES + HBUF_ELEMS * sizeof(__bf16), stream);

    lstm_persistent<<<dim3(NBLK), dim3(NTHR), 0, stream>>>(inp, Wih, Whh, bih, bhh,
                                                           out, flags, hbuf);
}